// Round 5
// baseline (581.024 us; speedup 1.0000x reference)
//
#include <hip/hip_runtime.h>

// grica power-whitening encoder, MI355X.
//   Kp k_prep    : zero C0 accumulator + split Wfc f32 -> bf16 hi/lo
//   K1 k_ygemm   : pure streaming MFMA split-bf16 GEMM y = x@Wfc^T.
//                  Barrier-free, LDS-free. 16 rows per wave, 64-row blocks,
//                  5 blocks/CU (launch_bounds cap 102 VGPR) for TLP latency
//                  hiding -- the GEMM is memory-latency-bound, not BW-bound.
//   K2 k_cov     : C0sum += y^T y via MFMA. Each wave owns a DISTINCT 32-row
//                  slab, accumulates its own full symmetric C contribution
//                  (10 upper 16x16 tile-pairs). Upper-triangular atomics only.
//   K3 k_whiten_ns : W = C^(-1/2) via coupled Newton-Schulz (10 iters).
//                  Symmetrizes block-upper C0sum on load; emits W pre-split
//                  as bf16 hi/lo for the MFMA yw pass.
//   K4 k_yw      : out = y @ W in place via MFMA split-bf16 (W symmetric ->
//                  B-fragments are contiguous row reads, L1-resident).
//                  16 rows per wave, 64-row blocks, 6 blocks/CU.

#define LDS_STRIDE 68    // whiten kernel only
#define NS_ITERS 10

typedef __attribute__((ext_vector_type(8))) short bf16x8;
typedef __attribute__((ext_vector_type(4))) float f32x4;

// split Wfc (64x256 f32) into truncation-split bf16 hi/lo, same layout.
// also zeroes the 64x64 C0 accumulator (first 4096 lanes).
__global__ __launch_bounds__(256) void k_prep(const float* __restrict__ Wfc,
                                              unsigned short* __restrict__ Wh,
                                              unsigned short* __restrict__ Wl,
                                              float* __restrict__ C0sum){
  const int i = blockIdx.x*256 + threadIdx.x;    // grid 64 -> 16384
  if (i < 4096) C0sum[i] = 0.f;
  const float f = Wfc[i];
  const unsigned b  = __float_as_uint(f);
  const unsigned hb = b & 0xFFFF0000u;
  Wh[i] = (unsigned short)(hb >> 16);
  Wl[i] = (unsigned short)(__float_as_uint(f - __uint_as_float(hb)) >> 16);
}

__device__ __forceinline__ void split8(float4 u, float4 v, bf16x8 &hi, bf16x8 &lo){
  const float f[8] = {u.x,u.y,u.z,u.w, v.x,v.y,v.z,v.w};
  #pragma unroll
  for (int i=0;i<8;i++){
    const unsigned b  = __float_as_uint(f[i]);
    const unsigned hb = b & 0xFFFF0000u;
    hi[i] = (short)(hb >> 16);
    lo[i] = (short)(__float_as_uint(f[i] - __uint_as_float(hb)) >> 16);
  }
}

#define MFMA16(a,b,c) __builtin_amdgcn_mfma_f32_16x16x32_bf16((a),(b),(c),0,0,0)

// Pure y = x @ Wfc^T. 64-row block, wave wv owns 16 rows: small per-wave
// state (accY = 16 VGPR) -> 5 blocks/CU residency for latency hiding.
__global__ __launch_bounds__(256,5) void k_ygemm(const float* __restrict__ x,
                                                 const unsigned short* __restrict__ Wh,
                                                 const unsigned short* __restrict__ Wl,
                                                 float* __restrict__ y,
                                                 int N){
  const int t  = threadIdx.x;
  const int wv = t>>6, l = t&63;
  const int lg = l>>4, lr = l&15;
  const long r0 = (long)blockIdx.x*64 + 16*wv;

  f32x4 accY[4];
  #pragma unroll
  for (int cb=0;cb<4;cb++) accY[cb] = (f32x4){0.f,0.f,0.f,0.f};

  #pragma unroll 2
  for (int ks=0; ks<8; ++ks){
    const int kl = 32*ks + 8*lg;                 // lane's 8 consecutive k
    const long row = r0 + lr;                    // A row = lane&15
    float4 a0, a1;
    if (row < (long)N){
      a0 = *(const float4*)&x[row*256 + kl];
      a1 = *(const float4*)&x[row*256 + kl + 4];
    } else {
      a0 = make_float4(0.f,0.f,0.f,0.f);
      a1 = make_float4(0.f,0.f,0.f,0.f);
    }
    bf16x8 ahi, alo;
    split8(a0, a1, ahi, alo);

    #pragma unroll
    for (int cb=0; cb<4; ++cb){
      const bf16x8 bhi = *(const bf16x8*)&Wh[(16*cb+lr)*256 + kl];
      const bf16x8 blo = *(const bf16x8*)&Wl[(16*cb+lr)*256 + kl];
      accY[cb] = MFMA16(ahi, bhi, accY[cb]);
      accY[cb] = MFMA16(alo, bhi, accY[cb]);
      accY[cb] = MFMA16(ahi, blo, accY[cb]);
    }
  }

  // C/D layout (m89-verified): col = lane&15, row = 4*(lane>>4)+i
  #pragma unroll
  for (int cb=0; cb<4; ++cb){
    #pragma unroll
    for (int i=0;i<4;i++){
      const long row = r0 + 4*lg + i;
      if (row < (long)N) y[row*64 + 16*cb + lr] = accY[cb][i];
    }
  }
}

// C0sum += y^T y. Wave wv owns rows [r0+32wv, r0+32wv+32): disjoint loads,
// each wave accumulates its own full symmetric C contribution.
// Shared k-map: k-slot j of lane (lg,lr) := slab row 8*lg+j. Valid since A
// and B fragments share the map and MFMA k-reduction is a pure sum.
__global__ __launch_bounds__(256,4) void k_cov(const float* __restrict__ y,
                                               float* __restrict__ C0sum,
                                               int N, int ntiles){
  const int t  = threadIdx.x;
  const int wv = t>>6, l = t&63;
  const int lg = l>>4, lr = l&15;

  f32x4 accC[10];
  #pragma unroll
  for (int p=0;p<10;p++) accC[p] = (f32x4){0.f,0.f,0.f,0.f};

  for (int tile = blockIdx.x; tile < ntiles; tile += gridDim.x){
    const long r0 = (long)tile*128 + 32*wv;     // wave's own slab
    bf16x8 fhi[4], flo[4];
    #pragma unroll
    for (int b=0;b<4;b++){
      float v[8];
      #pragma unroll
      for (int j=0;j<8;j++){
        const long row = r0 + 8*lg + j;
        v[j] = (row < (long)N) ? y[row*64 + 16*b + lr] : 0.f;
      }
      split8(make_float4(v[0],v[1],v[2],v[3]),
             make_float4(v[4],v[5],v[6],v[7]), fhi[b], flo[b]);
    }
    {
      int p = 0;
      #pragma unroll
      for (int a=0; a<4; ++a){
        #pragma unroll
        for (int b=a; b<4; ++b){
          accC[p] = MFMA16(fhi[a], fhi[b], accC[p]);
          accC[p] = MFMA16(flo[a], fhi[b], accC[p]);
          accC[p] = MFMA16(fhi[a], flo[b], accC[p]);
          ++p;
        }
      }
    }
  }

  // upper-block-triangular atomics only; whiten symmetrizes on load.
  {
    int p = 0;
    #pragma unroll
    for (int a=0; a<4; ++a){
      #pragma unroll
      for (int b=a; b<4; ++b){
        #pragma unroll
        for (int i=0;i<4;i++){
          const int m = 16*a + 4*lg + i;
          const int n = 16*b + lr;
          atomicAdd(&C0sum[m*64 + n], accC[p][i]);
        }
        ++p;
      }
    }
  }
}

#define WMAXRED(s) { s=fmaxf(s,__shfl_xor(s,32)); s=fmaxf(s,__shfl_xor(s,16)); \
  s=fmaxf(s,__shfl_xor(s,8)); s=fmaxf(s,__shfl_xor(s,4)); \
  s=fmaxf(s,__shfl_xor(s,2)); s=fmaxf(s,__shfl_xor(s,1)); }

// Coupled Newton-Schulz for C^(-1/2): A=C/tau (Gershgorin tau), Y=A, Z=I;
// T = 1.5I-0.5ZY; Y<-YT; Z<-TZ;  Z -> A^(-1/2);  W = Z/sqrt(tau).
// C0sum is block-upper-triangular (16x16 tiles): symmetrize on load.
// Emits W as split bf16 hi/lo (for the MFMA yw pass).
__global__ __launch_bounds__(256,1) void k_whiten_ns(const float* __restrict__ C0sum,
                                                     unsigned short* __restrict__ Wh2,
                                                     unsigned short* __restrict__ Wl2,
                                                     float invN){
  __shared__ __align__(16) float B0[64*LDS_STRIDE];
  __shared__ __align__(16) float B1[64*LDS_STRIDE];
  __shared__ __align__(16) float B2[64*LDS_STRIDE];
  __shared__ __align__(16) float B3[64*LDS_STRIDE];
  __shared__ float sred[8];

  const int t = threadIdx.x;
  const int w = t>>6, l = t&63;
  const int di = t>>2, djb = (t&3)*16;
  const int rg = l&3, cg = l>>2;
  const int row0 = 16*w + 4*rg;

  // thread's 16 cols live in col-tile (t&3); row-tile = di>>4.
  const bool upper = ((t&3) >= (di>>4));
  float4 cv[4];
  float psum = 0.f;
  #pragma unroll
  for (int c=0;c<4;c++){
    if (upper){
      cv[c] = *(const float4*)&C0sum[di*64 + djb + 4*c];
    } else {
      const int j0 = djb + 4*c;
      cv[c] = make_float4(C0sum[(j0+0)*64 + di], C0sum[(j0+1)*64 + di],
                          C0sum[(j0+2)*64 + di], C0sum[(j0+3)*64 + di]);
    }
    psum += fabsf(cv[c].x)+fabsf(cv[c].y)+fabsf(cv[c].z)+fabsf(cv[c].w);
  }
  psum *= invN;
  psum += __shfl_xor(psum,1);
  psum += __shfl_xor(psum,2);
  float m = psum;
  WMAXRED(m);
  if (l==0) sred[w] = m;
  __syncthreads();
  const float tau = fmaxf(fmaxf(sred[0],sred[1]), fmaxf(sred[2],sred[3]));
  const float sA = invN/tau;

  #pragma unroll
  for (int c=0;c<4;c++){
    float4 v4 = cv[c];
    v4.x*=sA; v4.y*=sA; v4.z*=sA; v4.w*=sA;
    *(float4*)&B0[di*LDS_STRIDE + djb + 4*c] = v4;
    const int j0 = djb + 4*c;
    *(float4*)&B1[di*LDS_STRIDE + j0] = make_float4(
        (di==j0+0)?1.f:0.f, (di==j0+1)?1.f:0.f,
        (di==j0+2)?1.f:0.f, (di==j0+3)?1.f:0.f);
  }
  __syncthreads();

  float *pY=B0, *pZ=B1, *pT=B2, *pU=B3;

  auto mm = [&](float* __restrict__ D, const float* __restrict__ A,
                const float* __restrict__ Bm, bool isT){
    float acc[4][4];
    #pragma unroll
    for (int i=0;i<4;i++)
      #pragma unroll
      for (int j=0;j<4;j++) acc[i][j] = 0.f;
    #pragma unroll 1
    for (int c=0;c<4;c++){
      float arr[4][16];
      #pragma unroll
      for (int ri=0;ri<4;ri++)
        #pragma unroll
        for (int k4=0;k4<4;k4++){
          const float4 a4 = *(const float4*)&A[(row0+ri)*LDS_STRIDE + 16*c + 4*k4];
          arr[ri][4*k4+0]=a4.x; arr[ri][4*k4+1]=a4.y;
          arr[ri][4*k4+2]=a4.z; arr[ri][4*k4+3]=a4.w;
        }
      #pragma unroll
      for (int kk=0;kk<16;kk++){
        const float4 b = *(const float4*)&Bm[(16*c+kk)*LDS_STRIDE + 4*cg];
        #pragma unroll
        for (int ri=0;ri<4;ri++){
          acc[ri][0] += arr[ri][kk]*b.x;
          acc[ri][1] += arr[ri][kk]*b.y;
          acc[ri][2] += arr[ri][kk]*b.z;
          acc[ri][3] += arr[ri][kk]*b.w;
        }
      }
    }
    if (isT){
      #pragma unroll
      for (int ri=0;ri<4;ri++)
        #pragma unroll
        for (int j=0;j<4;j++)
          acc[ri][j] = -0.5f*acc[ri][j] + ((row0+ri == 4*cg+j) ? 1.5f : 0.f);
    }
    #pragma unroll
    for (int ri=0;ri<4;ri++)
      *(float4*)&D[(row0+ri)*LDS_STRIDE + 4*cg] =
          make_float4(acc[ri][0],acc[ri][1],acc[ri][2],acc[ri][3]);
    __syncthreads();
  };

  #pragma unroll 1
  for (int it=0; it<NS_ITERS; ++it){
    mm(pT, pZ, pY, true);
    if (it < NS_ITERS-1) mm(pU, pY, pT, false);
    mm(pY, pT, pZ, false);
    float* oY=pY; float* oZ=pZ; float* oU=pU;
    pY = oU; pZ = oY; pU = oZ;
  }

  const float fs = rsqrtf(tau);
  #pragma unroll
  for (int c=0;c<4;c++){
    float4 z4 = *(const float4*)&pZ[di*LDS_STRIDE + djb + 4*c];
    const float zz[4] = {z4.x*fs, z4.y*fs, z4.z*fs, z4.w*fs};
    #pragma unroll
    for (int e=0;e<4;e++){
      const unsigned b  = __float_as_uint(zz[e]);
      const unsigned hb = b & 0xFFFF0000u;
      Wh2[di*64 + djb + 4*c + e] = (unsigned short)(hb >> 16);
      Wl2[di*64 + djb + 4*c + e] =
          (unsigned short)(__float_as_uint(zz[e] - __uint_as_float(hb)) >> 16);
    }
  }
}

// In-place MFMA: yio <- yio @ W. W symmetric: B-frag W[k][c]=W[c][k] is a
// contiguous row read of the split-bf16 W (16 KB, L1-resident).
// 64-row block, wave wv owns 16 rows exclusively: read-then-write, no barriers.
__global__ __launch_bounds__(256,6) void k_yw(float* yio,
                                              const unsigned short* __restrict__ Wh2,
                                              const unsigned short* __restrict__ Wl2,
                                              int N){
  const int t  = threadIdx.x;
  const int wv = t>>6, l = t&63;
  const int lg = l>>4, lr = l&15;
  const long r0 = (long)blockIdx.x*64 + 16*wv;

  f32x4 acc[4];
  #pragma unroll
  for (int cb=0;cb<4;cb++) acc[cb] = (f32x4){0.f,0.f,0.f,0.f};

  #pragma unroll
  for (int ks=0; ks<2; ++ks){
    const int kl = 32*ks + 8*lg;
    const long row = r0 + lr;
    float4 a0, a1;
    if (row < (long)N){
      a0 = *(const float4*)&yio[row*64 + kl];
      a1 = *(const float4*)&yio[row*64 + kl + 4];
    } else {
      a0 = make_float4(0.f,0.f,0.f,0.f);
      a1 = make_float4(0.f,0.f,0.f,0.f);
    }
    bf16x8 ahi, alo;
    split8(a0, a1, ahi, alo);

    #pragma unroll
    for (int cb=0; cb<4; ++cb){
      const bf16x8 bhi = *(const bf16x8*)&Wh2[(16*cb+lr)*64 + kl];
      const bf16x8 blo = *(const bf16x8*)&Wl2[(16*cb+lr)*64 + kl];
      acc[cb] = MFMA16(ahi, bhi, acc[cb]);
      acc[cb] = MFMA16(alo, bhi, acc[cb]);
      acc[cb] = MFMA16(ahi, blo, acc[cb]);
    }
  }

  #pragma unroll
  for (int cb=0; cb<4; ++cb){
    #pragma unroll
    for (int i=0;i<4;i++){
      const long row = r0 + 4*lg + i;
      if (row < (long)N) yio[row*64 + 16*cb + lr] = acc[cb][i];
    }
  }
}

extern "C" void kernel_launch(void* const* d_in, const int* in_sizes, int n_in,
                              void* d_out, int out_size, void* d_ws, size_t ws_size,
                              hipStream_t stream) {
  const float* x   = (const float*)d_in[0];   // [N,256]
  const float* Wfc = (const float*)d_in[1];   // [64,256]
  const float* R   = (const float*)d_in[2];   // unused: W = C^-1/2 exactly
  float* out = (float*)d_out;                 // [N,64] (holds y, then out)
  char*  ws  = (char*)d_ws;
  (void)R;

  float*          C0sum = (float*)(ws + 0);               // 16 KB
  unsigned short* Wh2   = (unsigned short*)(ws + 16384);  //  8 KB (split W)
  unsigned short* Wl2   = (unsigned short*)(ws + 24576);  //  8 KB
  unsigned short* Wh    = (unsigned short*)(ws + 32768);  // 32 KB (split Wfc)
  unsigned short* Wlo   = (unsigned short*)(ws + 65536);  // 32 KB

  const int N = in_sizes[0] / 256;
  const int nt128 = (N + 127)/128;
  const int nt64  = (N + 63)/64;

  k_prep     <<<64,    256, 0, stream>>>(Wfc, Wh, Wlo, C0sum);
  k_ygemm    <<<nt64,  256, 0, stream>>>(x, Wh, Wlo, out, N);
  k_cov      <<<512,   256, 0, stream>>>(out, C0sum, N, nt128);
  k_whiten_ns<<<1,     256, 0, stream>>>(C0sum, Wh2, Wl2, 1.0f/(float)N);
  k_yw       <<<nt64,  256, 0, stream>>>(out, Wh2, Wl2, N);
}

// Round 6
// 385.429 us; speedup vs baseline: 1.5075x; 1.5075x over previous
//
#include <hip/hip_runtime.h>

// grica power-whitening encoder, MI355X.
//   Kp k_prep    : zero C0 accumulator + split Wfc f32 -> bf16 hi/lo
//   K1 k_ygemm   : MFMA split-bf16 GEMM y = x@Wfc^T. 512-thread blocks,
//                  256-row tiles, 32 rows/wave (2 rb). B (Wh/Wl) staged ONCE
//                  per block into LDS (64KB working set thrashes L1; direct
//                  global B-reads cost ~2GB of L2 traffic). Row stride 264
//                  shorts = odd multiple of 16B -> ds_read_b128 at the
//                  conflict-free floor. x stays direct (read-once stream).
//   K2 k_cov     : C0sum += y^T y via MFMA, disjoint 32-row slabs per wave,
//                  upper-triangular atomics only.
//   K3 k_whiten_ns : W = C^(-1/2) via coupled Newton-Schulz (10 iters);
//                  symmetrizes block-upper C0sum; emits split-bf16 W.
//   K4 k_yw      : out = y @ W in place via MFMA split-bf16 (W symmetric,
//                  16KB L1-resident). 128-row blocks, 32 rows/wave.

#define LDS_STRIDE 68    // whiten kernel only
#define NS_ITERS 10
#define BSTRIDE 264      // ygemm LDS B row stride in shorts (256 + 8 pad)

typedef __attribute__((ext_vector_type(8))) short bf16x8;
typedef __attribute__((ext_vector_type(4))) float f32x4;

// split Wfc (64x256 f32) into truncation-split bf16 hi/lo, same layout.
// also zeroes the 64x64 C0 accumulator (first 4096 lanes).
__global__ __launch_bounds__(256) void k_prep(const float* __restrict__ Wfc,
                                              unsigned short* __restrict__ Wh,
                                              unsigned short* __restrict__ Wl,
                                              float* __restrict__ C0sum){
  const int i = blockIdx.x*256 + threadIdx.x;    // grid 64 -> 16384
  if (i < 4096) C0sum[i] = 0.f;
  const float f = Wfc[i];
  const unsigned b  = __float_as_uint(f);
  const unsigned hb = b & 0xFFFF0000u;
  Wh[i] = (unsigned short)(hb >> 16);
  Wl[i] = (unsigned short)(__float_as_uint(f - __uint_as_float(hb)) >> 16);
}

__device__ __forceinline__ void split8(float4 u, float4 v, bf16x8 &hi, bf16x8 &lo){
  const float f[8] = {u.x,u.y,u.z,u.w, v.x,v.y,v.z,v.w};
  #pragma unroll
  for (int i=0;i<8;i++){
    const unsigned b  = __float_as_uint(f[i]);
    const unsigned hb = b & 0xFFFF0000u;
    hi[i] = (short)(hb >> 16);
    lo[i] = (short)(__float_as_uint(f[i] - __uint_as_float(hb)) >> 16);
  }
}

#define MFMA16(a,b,c) __builtin_amdgcn_mfma_f32_16x16x32_bf16((a),(b),(c),0,0,0)

// y = x @ Wfc^T. 256-row block (8 waves x 32 rows), B staged in LDS.
__global__ __launch_bounds__(512,4) void k_ygemm(const float* __restrict__ x,
                                                 const unsigned short* __restrict__ Wh,
                                                 const unsigned short* __restrict__ Wl,
                                                 float* __restrict__ y,
                                                 int N){
  __shared__ __align__(16) unsigned short Bh[64*BSTRIDE];
  __shared__ __align__(16) unsigned short Bl[64*BSTRIDE];
  const int t  = threadIdx.x;
  const int wv = t>>6, l = t&63;
  const int lg = l>>4, lr = l&15;

  // one-time stage: 64 rows x 256 shorts each buffer, padded stride.
  #pragma unroll
  for (int q=0; q<4; ++q){
    const int idx = q*512 + t;              // 2048 chunks of 8 shorts
    const int row = idx>>5, c8 = (idx&31)*8;
    *(bf16x8*)&Bh[row*BSTRIDE + c8] = *(const bf16x8*)&Wh[row*256 + c8];
    *(bf16x8*)&Bl[row*BSTRIDE + c8] = *(const bf16x8*)&Wl[row*256 + c8];
  }
  __syncthreads();

  const long r0 = (long)blockIdx.x*256 + 32*wv;   // wave's 32 rows

  f32x4 accY[2][4];
  #pragma unroll
  for (int rb=0;rb<2;rb++)
    #pragma unroll
    for (int cb=0;cb<4;cb++) accY[rb][cb] = (f32x4){0.f,0.f,0.f,0.f};

  #pragma unroll 2
  for (int ks=0; ks<8; ++ks){
    const int kl = 32*ks + 8*lg;                 // lane's 8 consecutive k
    bf16x8 ahi[2], alo[2];
    #pragma unroll
    for (int rb=0; rb<2; ++rb){
      const long row = r0 + 16*rb + lr;          // A row = lane&15
      float4 a0, a1;
      if (row < (long)N){
        a0 = *(const float4*)&x[row*256 + kl];
        a1 = *(const float4*)&x[row*256 + kl + 4];
      } else {
        a0 = make_float4(0.f,0.f,0.f,0.f);
        a1 = make_float4(0.f,0.f,0.f,0.f);
      }
      split8(a0, a1, ahi[rb], alo[rb]);
    }
    #pragma unroll
    for (int cb=0; cb<4; ++cb){
      const bf16x8 bhi = *(const bf16x8*)&Bh[(16*cb+lr)*BSTRIDE + kl];
      const bf16x8 blo = *(const bf16x8*)&Bl[(16*cb+lr)*BSTRIDE + kl];
      #pragma unroll
      for (int rb=0; rb<2; ++rb){
        accY[rb][cb] = MFMA16(ahi[rb], bhi, accY[rb][cb]);
        accY[rb][cb] = MFMA16(alo[rb], bhi, accY[rb][cb]);
        accY[rb][cb] = MFMA16(ahi[rb], blo, accY[rb][cb]);
      }
    }
  }

  // C/D layout (m89-verified): col = lane&15, row = 4*(lane>>4)+i
  #pragma unroll
  for (int rb=0; rb<2; ++rb){
    #pragma unroll
    for (int cb=0; cb<4; ++cb){
      #pragma unroll
      for (int i=0;i<4;i++){
        const long row = r0 + 16*rb + 4*lg + i;
        if (row < (long)N) y[row*64 + 16*cb + lr] = accY[rb][cb][i];
      }
    }
  }
}

// C0sum += y^T y. Wave wv owns rows [r0+32wv, r0+32wv+32): disjoint loads,
// each wave accumulates its own full symmetric C contribution.
// Shared k-map: k-slot j of lane (lg,lr) := slab row 8*lg+j. Valid since A
// and B fragments share the map and MFMA k-reduction is a pure sum.
__global__ __launch_bounds__(256,4) void k_cov(const float* __restrict__ y,
                                               float* __restrict__ C0sum,
                                               int N, int ntiles){
  const int t  = threadIdx.x;
  const int wv = t>>6, l = t&63;
  const int lg = l>>4, lr = l&15;

  f32x4 accC[10];
  #pragma unroll
  for (int p=0;p<10;p++) accC[p] = (f32x4){0.f,0.f,0.f,0.f};

  for (int tile = blockIdx.x; tile < ntiles; tile += gridDim.x){
    const long r0 = (long)tile*128 + 32*wv;     // wave's own slab
    bf16x8 fhi[4], flo[4];
    #pragma unroll
    for (int b=0;b<4;b++){
      float v[8];
      #pragma unroll
      for (int j=0;j<8;j++){
        const long row = r0 + 8*lg + j;
        v[j] = (row < (long)N) ? y[row*64 + 16*b + lr] : 0.f;
      }
      split8(make_float4(v[0],v[1],v[2],v[3]),
             make_float4(v[4],v[5],v[6],v[7]), fhi[b], flo[b]);
    }
    {
      int p = 0;
      #pragma unroll
      for (int a=0; a<4; ++a){
        #pragma unroll
        for (int b=a; b<4; ++b){
          accC[p] = MFMA16(fhi[a], fhi[b], accC[p]);
          accC[p] = MFMA16(flo[a], fhi[b], accC[p]);
          accC[p] = MFMA16(fhi[a], flo[b], accC[p]);
          ++p;
        }
      }
    }
  }

  // upper-block-triangular atomics only; whiten symmetrizes on load.
  {
    int p = 0;
    #pragma unroll
    for (int a=0; a<4; ++a){
      #pragma unroll
      for (int b=a; b<4; ++b){
        #pragma unroll
        for (int i=0;i<4;i++){
          const int m = 16*a + 4*lg + i;
          const int n = 16*b + lr;
          atomicAdd(&C0sum[m*64 + n], accC[p][i]);
        }
        ++p;
      }
    }
  }
}

#define WMAXRED(s) { s=fmaxf(s,__shfl_xor(s,32)); s=fmaxf(s,__shfl_xor(s,16)); \
  s=fmaxf(s,__shfl_xor(s,8)); s=fmaxf(s,__shfl_xor(s,4)); \
  s=fmaxf(s,__shfl_xor(s,2)); s=fmaxf(s,__shfl_xor(s,1)); }

// Coupled Newton-Schulz for C^(-1/2): A=C/tau (Gershgorin tau), Y=A, Z=I;
// T = 1.5I-0.5ZY; Y<-YT; Z<-TZ;  Z -> A^(-1/2);  W = Z/sqrt(tau).
// C0sum is block-upper-triangular (16x16 tiles): symmetrize on load.
// Emits W as split bf16 hi/lo (for the MFMA yw pass).
__global__ __launch_bounds__(256,1) void k_whiten_ns(const float* __restrict__ C0sum,
                                                     unsigned short* __restrict__ Wh2,
                                                     unsigned short* __restrict__ Wl2,
                                                     float invN){
  __shared__ __align__(16) float B0[64*LDS_STRIDE];
  __shared__ __align__(16) float B1[64*LDS_STRIDE];
  __shared__ __align__(16) float B2[64*LDS_STRIDE];
  __shared__ __align__(16) float B3[64*LDS_STRIDE];
  __shared__ float sred[8];

  const int t = threadIdx.x;
  const int w = t>>6, l = t&63;
  const int di = t>>2, djb = (t&3)*16;
  const int rg = l&3, cg = l>>2;
  const int row0 = 16*w + 4*rg;

  // thread's 16 cols live in col-tile (t&3); row-tile = di>>4.
  const bool upper = ((t&3) >= (di>>4));
  float4 cv[4];
  float psum = 0.f;
  #pragma unroll
  for (int c=0;c<4;c++){
    if (upper){
      cv[c] = *(const float4*)&C0sum[di*64 + djb + 4*c];
    } else {
      const int j0 = djb + 4*c;
      cv[c] = make_float4(C0sum[(j0+0)*64 + di], C0sum[(j0+1)*64 + di],
                          C0sum[(j0+2)*64 + di], C0sum[(j0+3)*64 + di]);
    }
    psum += fabsf(cv[c].x)+fabsf(cv[c].y)+fabsf(cv[c].z)+fabsf(cv[c].w);
  }
  psum *= invN;
  psum += __shfl_xor(psum,1);
  psum += __shfl_xor(psum,2);
  float m = psum;
  WMAXRED(m);
  if (l==0) sred[w] = m;
  __syncthreads();
  const float tau = fmaxf(fmaxf(sred[0],sred[1]), fmaxf(sred[2],sred[3]));
  const float sA = invN/tau;

  #pragma unroll
  for (int c=0;c<4;c++){
    float4 v4 = cv[c];
    v4.x*=sA; v4.y*=sA; v4.z*=sA; v4.w*=sA;
    *(float4*)&B0[di*LDS_STRIDE + djb + 4*c] = v4;
    const int j0 = djb + 4*c;
    *(float4*)&B1[di*LDS_STRIDE + j0] = make_float4(
        (di==j0+0)?1.f:0.f, (di==j0+1)?1.f:0.f,
        (di==j0+2)?1.f:0.f, (di==j0+3)?1.f:0.f);
  }
  __syncthreads();

  float *pY=B0, *pZ=B1, *pT=B2, *pU=B3;

  auto mm = [&](float* __restrict__ D, const float* __restrict__ A,
                const float* __restrict__ Bm, bool isT){
    float acc[4][4];
    #pragma unroll
    for (int i=0;i<4;i++)
      #pragma unroll
      for (int j=0;j<4;j++) acc[i][j] = 0.f;
    #pragma unroll 1
    for (int c=0;c<4;c++){
      float arr[4][16];
      #pragma unroll
      for (int ri=0;ri<4;ri++)
        #pragma unroll
        for (int k4=0;k4<4;k4++){
          const float4 a4 = *(const float4*)&A[(row0+ri)*LDS_STRIDE + 16*c + 4*k4];
          arr[ri][4*k4+0]=a4.x; arr[ri][4*k4+1]=a4.y;
          arr[ri][4*k4+2]=a4.z; arr[ri][4*k4+3]=a4.w;
        }
      #pragma unroll
      for (int kk=0;kk<16;kk++){
        const float4 b = *(const float4*)&Bm[(16*c+kk)*LDS_STRIDE + 4*cg];
        #pragma unroll
        for (int ri=0;ri<4;ri++){
          acc[ri][0] += arr[ri][kk]*b.x;
          acc[ri][1] += arr[ri][kk]*b.y;
          acc[ri][2] += arr[ri][kk]*b.z;
          acc[ri][3] += arr[ri][kk]*b.w;
        }
      }
    }
    if (isT){
      #pragma unroll
      for (int ri=0;ri<4;ri++)
        #pragma unroll
        for (int j=0;j<4;j++)
          acc[ri][j] = -0.5f*acc[ri][j] + ((row0+ri == 4*cg+j) ? 1.5f : 0.f);
    }
    #pragma unroll
    for (int ri=0;ri<4;ri++)
      *(float4*)&D[(row0+ri)*LDS_STRIDE + 4*cg] =
          make_float4(acc[ri][0],acc[ri][1],acc[ri][2],acc[ri][3]);
    __syncthreads();
  };

  #pragma unroll 1
  for (int it=0; it<NS_ITERS; ++it){
    mm(pT, pZ, pY, true);
    if (it < NS_ITERS-1) mm(pU, pY, pT, false);
    mm(pY, pT, pZ, false);
    float* oY=pY; float* oZ=pZ; float* oU=pU;
    pY = oU; pZ = oY; pU = oZ;
  }

  const float fs = rsqrtf(tau);
  #pragma unroll
  for (int c=0;c<4;c++){
    float4 z4 = *(const float4*)&pZ[di*LDS_STRIDE + djb + 4*c];
    const float zz[4] = {z4.x*fs, z4.y*fs, z4.z*fs, z4.w*fs};
    #pragma unroll
    for (int e=0;e<4;e++){
      const unsigned b  = __float_as_uint(zz[e]);
      const unsigned hb = b & 0xFFFF0000u;
      Wh2[di*64 + djb + 4*c + e] = (unsigned short)(hb >> 16);
      Wl2[di*64 + djb + 4*c + e] =
          (unsigned short)(__float_as_uint(zz[e] - __uint_as_float(hb)) >> 16);
    }
  }
}

// In-place MFMA: yio[128-tile] <- yio @ W. W symmetric: B-frag W[k][c]=W[c][k]
// is a contiguous row read of the split-bf16 W (16 KB, L1-resident).
// Wave wv owns rows [32wv,32wv+32) exclusively: read-then-write, no barriers.
__global__ __launch_bounds__(256,4) void k_yw(float* yio,
                                              const unsigned short* __restrict__ Wh2,
                                              const unsigned short* __restrict__ Wl2,
                                              int N){
  const int t  = threadIdx.x;
  const int wv = t>>6, l = t&63;
  const int lg = l>>4, lr = l&15;
  const long r0 = (long)blockIdx.x*128;

  f32x4 acc[2][4];
  #pragma unroll
  for (int rb=0;rb<2;rb++)
    #pragma unroll
    for (int cb=0;cb<4;cb++) acc[rb][cb] = (f32x4){0.f,0.f,0.f,0.f};

  #pragma unroll
  for (int ks=0; ks<2; ++ks){
    const int kl = 32*ks + 8*lg;
    bf16x8 ahi[2], alo[2];
    #pragma unroll
    for (int rb=0; rb<2; ++rb){
      const long row = r0 + 32*wv + 16*rb + lr;
      float4 a0, a1;
      if (row < (long)N){
        a0 = *(const float4*)&yio[row*64 + kl];
        a1 = *(const float4*)&yio[row*64 + kl + 4];
      } else {
        a0 = make_float4(0.f,0.f,0.f,0.f);
        a1 = make_float4(0.f,0.f,0.f,0.f);
      }
      split8(a0, a1, ahi[rb], alo[rb]);
    }
    #pragma unroll
    for (int cb=0; cb<4; ++cb){
      const bf16x8 bhi = *(const bf16x8*)&Wh2[(16*cb+lr)*64 + kl];
      const bf16x8 blo = *(const bf16x8*)&Wl2[(16*cb+lr)*64 + kl];
      #pragma unroll
      for (int rb=0; rb<2; ++rb){
        acc[rb][cb] = MFMA16(ahi[rb], bhi, acc[rb][cb]);
        acc[rb][cb] = MFMA16(alo[rb], bhi, acc[rb][cb]);
        acc[rb][cb] = MFMA16(ahi[rb], blo, acc[rb][cb]);
      }
    }
  }

  #pragma unroll
  for (int rb=0; rb<2; ++rb){
    #pragma unroll
    for (int cb=0; cb<4; ++cb){
      #pragma unroll
      for (int i=0;i<4;i++){
        const long row = r0 + 32*wv + 16*rb + 4*lg + i;
        if (row < (long)N) yio[row*64 + 16*cb + lr] = acc[rb][cb][i];
      }
    }
  }
}

extern "C" void kernel_launch(void* const* d_in, const int* in_sizes, int n_in,
                              void* d_out, int out_size, void* d_ws, size_t ws_size,
                              hipStream_t stream) {
  const float* x   = (const float*)d_in[0];   // [N,256]
  const float* Wfc = (const float*)d_in[1];   // [64,256]
  const float* R   = (const float*)d_in[2];   // unused: W = C^-1/2 exactly
  float* out = (float*)d_out;                 // [N,64] (holds y, then out)
  char*  ws  = (char*)d_ws;
  (void)R;

  float*          C0sum = (float*)(ws + 0);               // 16 KB
  unsigned short* Wh2   = (unsigned short*)(ws + 16384);  //  8 KB (split W)
  unsigned short* Wl2   = (unsigned short*)(ws + 24576);  //  8 KB
  unsigned short* Wh    = (unsigned short*)(ws + 32768);  // 32 KB (split Wfc)
  unsigned short* Wlo   = (unsigned short*)(ws + 65536);  // 32 KB

  const int N = in_sizes[0] / 256;
  const int nt128 = (N + 127)/128;
  const int nt256 = (N + 255)/256;

  k_prep     <<<64,    256, 0, stream>>>(Wfc, Wh, Wlo, C0sum);
  k_ygemm    <<<nt256, 512, 0, stream>>>(x, Wh, Wlo, out, N);
  k_cov      <<<512,   256, 0, stream>>>(out, C0sum, N, nt128);
  k_whiten_ns<<<1,     256, 0, stream>>>(C0sum, Wh2, Wl2, 1.0f/(float)N);
  k_yw       <<<nt128, 256, 0, stream>>>(out, Wh2, Wl2, N);
}

// Round 7
// 326.008 us; speedup vs baseline: 1.7822x; 1.1823x over previous
//
#include <hip/hip_runtime.h>

// grica power-whitening encoder, MI355X.
//   Kp k_prep    : zero C0 accumulator + split Wfc f32 -> bf16 hi/lo
//   K1 k_pass    : fused MFMA split-bf16 GEMM y = x@Wfc^T AND C0sum += y^T y.
//                  512-thread blocks, grid-stride over 256-row tiles, B staged
//                  once per block in LDS (padded stride, conflict-free).
//                  Per tile: y-GEMM (accY) -> y store -> in-register split ->
//                  30 cov MFMAs into persistent accC[10] (upper pairs).
//                  End: block-level LDS reduction (reuses B LDS) -> one
//                  atomicAdd set per block (512 x 2560 atomics total).
//   K3 k_whiten_ns : W = C^(-1/2) via coupled Newton-Schulz (10 iters);
//                  symmetrizes block-upper C0sum; emits split-bf16 W.
//   K4 k_yw      : out = y @ W in place via MFMA split-bf16 (W symmetric,
//                  16KB L1-resident). 128-row blocks, 32 rows/wave.

#define LDS_STRIDE 68    // whiten kernel only
#define NS_ITERS 10
#define BSTRIDE 264      // k_pass LDS B row stride in shorts (256 + 8 pad)

typedef __attribute__((ext_vector_type(8))) short bf16x8;
typedef __attribute__((ext_vector_type(4))) float f32x4;

// split Wfc (64x256 f32) into truncation-split bf16 hi/lo, same layout.
// also zeroes the 64x64 C0 accumulator (first 4096 lanes).
__global__ __launch_bounds__(256) void k_prep(const float* __restrict__ Wfc,
                                              unsigned short* __restrict__ Wh,
                                              unsigned short* __restrict__ Wl,
                                              float* __restrict__ C0sum){
  const int i = blockIdx.x*256 + threadIdx.x;    // grid 64 -> 16384
  if (i < 4096) C0sum[i] = 0.f;
  const float f = Wfc[i];
  const unsigned b  = __float_as_uint(f);
  const unsigned hb = b & 0xFFFF0000u;
  Wh[i] = (unsigned short)(hb >> 16);
  Wl[i] = (unsigned short)(__float_as_uint(f - __uint_as_float(hb)) >> 16);
}

__device__ __forceinline__ void split8(float4 u, float4 v, bf16x8 &hi, bf16x8 &lo){
  const float f[8] = {u.x,u.y,u.z,u.w, v.x,v.y,v.z,v.w};
  #pragma unroll
  for (int i=0;i<8;i++){
    const unsigned b  = __float_as_uint(f[i]);
    const unsigned hb = b & 0xFFFF0000u;
    hi[i] = (short)(hb >> 16);
    lo[i] = (short)(__float_as_uint(f[i] - __uint_as_float(hb)) >> 16);
  }
}

#define MFMA16(a,b,c) __builtin_amdgcn_mfma_f32_16x16x32_bf16((a),(b),(c),0,0,0)

// Fused y-GEMM + covariance. 256-row tiles (8 waves x 32 rows), grid-stride.
__global__ __launch_bounds__(512,4) void k_pass(const float* __restrict__ x,
                                                const unsigned short* __restrict__ Wh,
                                                const unsigned short* __restrict__ Wl,
                                                float* __restrict__ y,
                                                float* __restrict__ C0sum,
                                                int N, int ntiles){
  __shared__ __align__(16) unsigned short SMEM[2*64*BSTRIDE];
  unsigned short* Bh = SMEM;
  unsigned short* Bl = SMEM + 64*BSTRIDE;
  const int t  = threadIdx.x;
  const int wv = t>>6, l = t&63;
  const int lg = l>>4, lr = l&15;

  // one-time stage: 64 rows x 256 shorts each buffer, padded stride.
  #pragma unroll
  for (int q=0; q<4; ++q){
    const int idx = q*512 + t;              // 2048 chunks of 8 shorts
    const int row = idx>>5, c8 = (idx&31)*8;
    *(bf16x8*)&Bh[row*BSTRIDE + c8] = *(const bf16x8*)&Wh[row*256 + c8];
    *(bf16x8*)&Bl[row*BSTRIDE + c8] = *(const bf16x8*)&Wl[row*256 + c8];
  }
  __syncthreads();

  // persistent symmetric-C accumulators: upper pairs (a<=b)
  f32x4 accC[10];
  #pragma unroll
  for (int p=0;p<10;p++) accC[p] = (f32x4){0.f,0.f,0.f,0.f};

  for (int tile = blockIdx.x; tile < ntiles; tile += gridDim.x){
    const long r0 = (long)tile*256 + 32*wv;   // wave's 32 rows

    f32x4 accY[2][4];
    #pragma unroll
    for (int rb=0;rb<2;rb++)
      #pragma unroll
      for (int cb=0;cb<4;cb++) accY[rb][cb] = (f32x4){0.f,0.f,0.f,0.f};

    #pragma unroll 1
    for (int ks=0; ks<8; ++ks){
      const int kl = 32*ks + 8*lg;                 // lane's 8 consecutive k
      bf16x8 ahi[2], alo[2];
      #pragma unroll
      for (int rb=0; rb<2; ++rb){
        const long row = r0 + 16*rb + lr;          // A row = lane&15
        float4 a0, a1;
        if (row < (long)N){
          a0 = *(const float4*)&x[row*256 + kl];
          a1 = *(const float4*)&x[row*256 + kl + 4];
        } else {
          a0 = make_float4(0.f,0.f,0.f,0.f);
          a1 = make_float4(0.f,0.f,0.f,0.f);
        }
        split8(a0, a1, ahi[rb], alo[rb]);
      }
      #pragma unroll
      for (int cb=0; cb<4; ++cb){
        const bf16x8 bhi = *(const bf16x8*)&Bh[(16*cb+lr)*BSTRIDE + kl];
        const bf16x8 blo = *(const bf16x8*)&Bl[(16*cb+lr)*BSTRIDE + kl];
        #pragma unroll
        for (int rb=0; rb<2; ++rb){
          accY[rb][cb] = MFMA16(ahi[rb], bhi, accY[rb][cb]);
          accY[rb][cb] = MFMA16(alo[rb], bhi, accY[rb][cb]);
          accY[rb][cb] = MFMA16(ahi[rb], blo, accY[rb][cb]);
        }
      }
    }

    // y -> global. C/D layout (m89-verified): col = lane&15, row = 4*(lane>>4)+i
    #pragma unroll
    for (int rb=0; rb<2; ++rb){
      #pragma unroll
      for (int cb=0; cb<4; ++cb){
        #pragma unroll
        for (int i=0;i<4;i++){
          const long row = r0 + 16*rb + 4*lg + i;
          if (row < (long)N) y[row*64 + 16*cb + lr] = accY[rb][cb][i];
        }
      }
    }

    // in-register C contribution (K=32 = this wave's rows).
    // k-slot j of lane (lg,lr) := local row 16*(j>>2)+4*lg+(j&3); A and B
    // fragments share the map, MFMA k-reduction is a pure sum (r2-verified).
    bf16x8 chi[4], clo[4];
    #pragma unroll
    for (int g=0; g<4; ++g){
      const float4 u = make_float4(accY[0][g][0],accY[0][g][1],accY[0][g][2],accY[0][g][3]);
      const float4 v = make_float4(accY[1][g][0],accY[1][g][1],accY[1][g][2],accY[1][g][3]);
      split8(u, v, chi[g], clo[g]);
    }
    {
      int p = 0;
      #pragma unroll
      for (int a=0; a<4; ++a){
        #pragma unroll
        for (int b=a; b<4; ++b){
          accC[p] = MFMA16(chi[a], chi[b], accC[p]);
          accC[p] = MFMA16(clo[a], chi[b], accC[p]);
          accC[p] = MFMA16(chi[a], clo[b], accC[p]);
          ++p;
        }
      }
    }
  }

  // ---- block reduction of accC (8 waves -> 1), reusing the B LDS.
  __syncthreads();                       // B no longer needed
  float* red = (float*)SMEM;             // 4*10*256 floats = 40 KB (fits 66 KB)
  if (wv < 4){
    #pragma unroll
    for (int p=0;p<10;p++)
      *(f32x4*)&red[(wv*10+p)*256 + l*4] = accC[p];
  }
  __syncthreads();
  if (wv >= 4){
    #pragma unroll
    for (int p=0;p<10;p++){
      f32x4 v = *(f32x4*)&red[((wv-4)*10+p)*256 + l*4];
      v += accC[p];
      *(f32x4*)&red[((wv-4)*10+p)*256 + l*4] = v;
    }
  }
  __syncthreads();

  // one atomicAdd set per block: 2560 upper-triangle elements.
  for (int e = t; e < 2560; e += 512){
    const int p = e>>8, li = (e>>2)&63, i = e&3;
    const float s = red[(0*10+p)*256 + li*4 + i] + red[(1*10+p)*256 + li*4 + i]
                  + red[(2*10+p)*256 + li*4 + i] + red[(3*10+p)*256 + li*4 + i];
    const int a = (p>=4) + (p>=7) + (p>=9);
    const int off = (a==0) ? 0 : (a==1) ? 4 : (a==2) ? 7 : 9;
    const int b = a + (p - off);
    const int m = 16*a + 4*(li>>4) + i;
    const int n = 16*b + (li&15);
    atomicAdd(&C0sum[m*64 + n], s);
  }
}

#define WMAXRED(s) { s=fmaxf(s,__shfl_xor(s,32)); s=fmaxf(s,__shfl_xor(s,16)); \
  s=fmaxf(s,__shfl_xor(s,8)); s=fmaxf(s,__shfl_xor(s,4)); \
  s=fmaxf(s,__shfl_xor(s,2)); s=fmaxf(s,__shfl_xor(s,1)); }

// Coupled Newton-Schulz for C^(-1/2): A=C/tau (Gershgorin tau), Y=A, Z=I;
// T = 1.5I-0.5ZY; Y<-YT; Z<-TZ;  Z -> A^(-1/2);  W = Z/sqrt(tau).
// C0sum is block-upper-triangular (16x16 tiles): symmetrize on load.
// Emits W as split bf16 hi/lo (for the MFMA yw pass).
__global__ __launch_bounds__(256,1) void k_whiten_ns(const float* __restrict__ C0sum,
                                                     unsigned short* __restrict__ Wh2,
                                                     unsigned short* __restrict__ Wl2,
                                                     float invN){
  __shared__ __align__(16) float B0[64*LDS_STRIDE];
  __shared__ __align__(16) float B1[64*LDS_STRIDE];
  __shared__ __align__(16) float B2[64*LDS_STRIDE];
  __shared__ __align__(16) float B3[64*LDS_STRIDE];
  __shared__ float sred[8];

  const int t = threadIdx.x;
  const int w = t>>6, l = t&63;
  const int di = t>>2, djb = (t&3)*16;
  const int rg = l&3, cg = l>>2;
  const int row0 = 16*w + 4*rg;

  // thread's 16 cols live in col-tile (t&3); row-tile = di>>4.
  const bool upper = ((t&3) >= (di>>4));
  float4 cv[4];
  float psum = 0.f;
  #pragma unroll
  for (int c=0;c<4;c++){
    if (upper){
      cv[c] = *(const float4*)&C0sum[di*64 + djb + 4*c];
    } else {
      const int j0 = djb + 4*c;
      cv[c] = make_float4(C0sum[(j0+0)*64 + di], C0sum[(j0+1)*64 + di],
                          C0sum[(j0+2)*64 + di], C0sum[(j0+3)*64 + di]);
    }
    psum += fabsf(cv[c].x)+fabsf(cv[c].y)+fabsf(cv[c].z)+fabsf(cv[c].w);
  }
  psum *= invN;
  psum += __shfl_xor(psum,1);
  psum += __shfl_xor(psum,2);
  float m = psum;
  WMAXRED(m);
  if (l==0) sred[w] = m;
  __syncthreads();
  const float tau = fmaxf(fmaxf(sred[0],sred[1]), fmaxf(sred[2],sred[3]));
  const float sA = invN/tau;

  #pragma unroll
  for (int c=0;c<4;c++){
    float4 v4 = cv[c];
    v4.x*=sA; v4.y*=sA; v4.z*=sA; v4.w*=sA;
    *(float4*)&B0[di*LDS_STRIDE + djb + 4*c] = v4;
    const int j0 = djb + 4*c;
    *(float4*)&B1[di*LDS_STRIDE + j0] = make_float4(
        (di==j0+0)?1.f:0.f, (di==j0+1)?1.f:0.f,
        (di==j0+2)?1.f:0.f, (di==j0+3)?1.f:0.f);
  }
  __syncthreads();

  float *pY=B0, *pZ=B1, *pT=B2, *pU=B3;

  auto mm = [&](float* __restrict__ D, const float* __restrict__ A,
                const float* __restrict__ Bm, bool isT){
    float acc[4][4];
    #pragma unroll
    for (int i=0;i<4;i++)
      #pragma unroll
      for (int j=0;j<4;j++) acc[i][j] = 0.f;
    #pragma unroll 1
    for (int c=0;c<4;c++){
      float arr[4][16];
      #pragma unroll
      for (int ri=0;ri<4;ri++)
        #pragma unroll
        for (int k4=0;k4<4;k4++){
          const float4 a4 = *(const float4*)&A[(row0+ri)*LDS_STRIDE + 16*c + 4*k4];
          arr[ri][4*k4+0]=a4.x; arr[ri][4*k4+1]=a4.y;
          arr[ri][4*k4+2]=a4.z; arr[ri][4*k4+3]=a4.w;
        }
      #pragma unroll
      for (int kk=0;kk<16;kk++){
        const float4 b = *(const float4*)&Bm[(16*c+kk)*LDS_STRIDE + 4*cg];
        #pragma unroll
        for (int ri=0;ri<4;ri++){
          acc[ri][0] += arr[ri][kk]*b.x;
          acc[ri][1] += arr[ri][kk]*b.y;
          acc[ri][2] += arr[ri][kk]*b.z;
          acc[ri][3] += arr[ri][kk]*b.w;
        }
      }
    }
    if (isT){
      #pragma unroll
      for (int ri=0;ri<4;ri++)
        #pragma unroll
        for (int j=0;j<4;j++)
          acc[ri][j] = -0.5f*acc[ri][j] + ((row0+ri == 4*cg+j) ? 1.5f : 0.f);
    }
    #pragma unroll
    for (int ri=0;ri<4;ri++)
      *(float4*)&D[(row0+ri)*LDS_STRIDE + 4*cg] =
          make_float4(acc[ri][0],acc[ri][1],acc[ri][2],acc[ri][3]);
    __syncthreads();
  };

  #pragma unroll 1
  for (int it=0; it<NS_ITERS; ++it){
    mm(pT, pZ, pY, true);
    if (it < NS_ITERS-1) mm(pU, pY, pT, false);
    mm(pY, pT, pZ, false);
    float* oY=pY; float* oZ=pZ; float* oU=pU;
    pY = oU; pZ = oY; pU = oZ;
  }

  const float fs = rsqrtf(tau);
  #pragma unroll
  for (int c=0;c<4;c++){
    float4 z4 = *(const float4*)&pZ[di*LDS_STRIDE + djb + 4*c];
    const float zz[4] = {z4.x*fs, z4.y*fs, z4.z*fs, z4.w*fs};
    #pragma unroll
    for (int e=0;e<4;e++){
      const unsigned b  = __float_as_uint(zz[e]);
      const unsigned hb = b & 0xFFFF0000u;
      Wh2[di*64 + djb + 4*c + e] = (unsigned short)(hb >> 16);
      Wl2[di*64 + djb + 4*c + e] =
          (unsigned short)(__float_as_uint(zz[e] - __uint_as_float(hb)) >> 16);
    }
  }
}

// In-place MFMA: yio[128-tile] <- yio @ W. W symmetric: B-frag W[k][c]=W[c][k]
// is a contiguous row read of the split-bf16 W (16 KB, L1-resident).
// Wave wv owns rows [32wv,32wv+32) exclusively: read-then-write, no barriers.
__global__ __launch_bounds__(256,4) void k_yw(float* yio,
                                              const unsigned short* __restrict__ Wh2,
                                              const unsigned short* __restrict__ Wl2,
                                              int N){
  const int t  = threadIdx.x;
  const int wv = t>>6, l = t&63;
  const int lg = l>>4, lr = l&15;
  const long r0 = (long)blockIdx.x*128;

  f32x4 acc[2][4];
  #pragma unroll
  for (int rb=0;rb<2;rb++)
    #pragma unroll
    for (int cb=0;cb<4;cb++) acc[rb][cb] = (f32x4){0.f,0.f,0.f,0.f};

  #pragma unroll
  for (int ks=0; ks<2; ++ks){
    const int kl = 32*ks + 8*lg;
    bf16x8 ahi[2], alo[2];
    #pragma unroll
    for (int rb=0; rb<2; ++rb){
      const long row = r0 + 32*wv + 16*rb + lr;
      float4 a0, a1;
      if (row < (long)N){
        a0 = *(const float4*)&yio[row*64 + kl];
        a1 = *(const float4*)&yio[row*64 + kl + 4];
      } else {
        a0 = make_float4(0.f,0.f,0.f,0.f);
        a1 = make_float4(0.f,0.f,0.f,0.f);
      }
      split8(a0, a1, ahi[rb], alo[rb]);
    }
    #pragma unroll
    for (int cb=0; cb<4; ++cb){
      const bf16x8 bhi = *(const bf16x8*)&Wh2[(16*cb+lr)*64 + kl];
      const bf16x8 blo = *(const bf16x8*)&Wl2[(16*cb+lr)*64 + kl];
      #pragma unroll
      for (int rb=0; rb<2; ++rb){
        acc[rb][cb] = MFMA16(ahi[rb], bhi, acc[rb][cb]);
        acc[rb][cb] = MFMA16(alo[rb], bhi, acc[rb][cb]);
        acc[rb][cb] = MFMA16(ahi[rb], blo, acc[rb][cb]);
      }
    }
  }

  #pragma unroll
  for (int rb=0; rb<2; ++rb){
    #pragma unroll
    for (int cb=0; cb<4; ++cb){
      #pragma unroll
      for (int i=0;i<4;i++){
        const long row = r0 + 32*wv + 16*rb + 4*lg + i;
        if (row < (long)N) yio[row*64 + 16*cb + lr] = acc[rb][cb][i];
      }
    }
  }
}

extern "C" void kernel_launch(void* const* d_in, const int* in_sizes, int n_in,
                              void* d_out, int out_size, void* d_ws, size_t ws_size,
                              hipStream_t stream) {
  const float* x   = (const float*)d_in[0];   // [N,256]
  const float* Wfc = (const float*)d_in[1];   // [64,256]
  const float* R   = (const float*)d_in[2];   // unused: W = C^-1/2 exactly
  float* out = (float*)d_out;                 // [N,64] (holds y, then out)
  char*  ws  = (char*)d_ws;
  (void)R;

  float*          C0sum = (float*)(ws + 0);               // 16 KB
  unsigned short* Wh2   = (unsigned short*)(ws + 16384);  //  8 KB (split W)
  unsigned short* Wl2   = (unsigned short*)(ws + 24576);  //  8 KB
  unsigned short* Wh    = (unsigned short*)(ws + 32768);  // 32 KB (split Wfc)
  unsigned short* Wlo   = (unsigned short*)(ws + 65536);  // 32 KB

  const int N = in_sizes[0] / 256;
  const int nt128 = (N + 127)/128;
  const int nt256 = (N + 255)/256;

  k_prep     <<<64,    256, 0, stream>>>(Wfc, Wh, Wlo, C0sum);
  k_pass     <<<512,   512, 0, stream>>>(x, Wh, Wlo, out, C0sum, N, nt256);
  k_whiten_ns<<<1,     256, 0, stream>>>(C0sum, Wh2, Wl2, 1.0f/(float)N);
  k_yw       <<<nt128, 256, 0, stream>>>(out, Wh2, Wl2, N);
}